// Round 17
// baseline (115.013 us; speedup 1.0000x reference)
//
#include <hip/hip_runtime.h>
#include <math.h>

#define D 256
#define K2 512          // 2*D
#define BATCH 1024      // n2
#define N1 11264        // n1 = B*(1+10)
#define S0 25
#define S1 10
#define RB0 44          // rows per layer0 block: 11264/44 = 256 blocks = 1/CU
#define RP 48           // padded rows (3 x 16 fragments)

typedef __bf16 bf16x8 __attribute__((ext_vector_type(8)));
typedef __bf16 bf16x4 __attribute__((ext_vector_type(4)));
typedef float  f32x4  __attribute__((ext_vector_type(4)));

// ---------------------------------------------------------------------------
// convert_w: W0, W1 fp32 -> bf16. ~3us. R16 model: the layer0 GEMM tail is
// W0-STAGING-BYTE-bound on the per-CU load pipe (512KB fp32/CU ~ 21us of
// pipe time). bf16 staging halves it. R14's spill confound is controlled
// this round via launch_bounds(256,1) (grid=1 block/CU anyway).
// ---------------------------------------------------------------------------
__global__ __launch_bounds__(256) void convert_w(
        const float* __restrict__ W0, const float* __restrict__ W1,
        __bf16* __restrict__ Wb0, __bf16* __restrict__ Wb1) {
    int i = blockIdx.x * 256 + threadIdx.x;   // 65536 threads
    const float* src = (i < 32768) ? W0 : W1;
    __bf16* dst = (i < 32768) ? Wb0 : Wb1;
    int j = i & 32767;
    float4 v = ((const float4*)src)[j];
    bf16x4 o = { (__bf16)v.x, (__bf16)v.y, (__bf16)v.z, (__bf16)v.w };
    *(bf16x4*)(dst + (size_t)j * 4) = o;
}

// ---------------------------------------------------------------------------
// fused_layer0 (RB=44, grid=256 = 1 block/CU; bf16 B-staging):
//   phase 1 (gather): wave w gathers rows [11w, 11w+11): self + mean of 25
//     neighbor fp32 rows -> bf16 -> swizzled full-K LDS A-tile [48][512].
//   phase 2 (GEMM): 8 k-tiles of 64; B staged from BF16 Wb0 (8 uint4/thread,
//     reg-prefetched; 256KB/CU instead of fp32's 512KB - halves the
//     load-pipe cost of the gemm tail); 3 row-frags x 4 col-frags per wave.
//   epilogue: bias + relu + row-l2norm -> h1b (bf16), rows < 44 only.
// launch_bounds(256,1): grid==CU count, so 2-block residency is impossible
// anyway; the relaxed VGPR cap (512) prevents R14's spill (v[25] + rb[8]).
// Fragment mapping (m89): A/B lane l: row/col=l&15, k=(l>>4)*8+i.
// C/D: col=l&15, row=(l>>4)*4+reg.
// ---------------------------------------------------------------------------
__global__ __launch_bounds__(256, 1) void fused_layer0(
        const float* __restrict__ feat, const __bf16* __restrict__ Wb0,
        const float* __restrict__ b0, const int* __restrict__ nodes2,
        const int* __restrict__ neigh2, const int* __restrict__ neigh1,
        __bf16* __restrict__ h1b) {
    __shared__ __bf16 Atile[RP * 512];   // 48KB, swizzled granules of 8 bf16
    __shared__ __bf16 Bs[256 * 64];      // 32KB, tile16 layout
    __shared__ float ssLDS[4][RP];
    __shared__ float invLDS[RP];

    const int tid = threadIdx.x;
    const int lane = tid & 63;
    const int w = tid >> 6;
    const int rl = lane & 15;
    const int g = lane >> 4;
    const int row0 = blockIdx.x * RB0;

    // ---- B prologue loads (k0 = 0), bf16, 8 x uint4 per thread ----
    uint4 rb[8];
#pragma unroll
    for (int s = 0; s < 8; ++s) {
        int i = tid + s * 256;
        int cg = i >> 7, kc = (i >> 4) & 7, lo = i & 15;
        rb[s] = *(const uint4*)(Wb0 + (size_t)(cg * 16 + lo) * K2 + kc * 8);
    }

    // ---- gather phase: wave w handles rows [11w, 11w+11) ----
#pragma unroll 1
    for (int r = w * 11; r < w * 11 + 11; ++r) {
        const int gr = row0 + r;
        const int self_idx = (gr < BATCH) ? nodes2[gr] : neigh2[gr - BATCH];
        const int* nb = neigh1 + (size_t)gr * S0;
        int idx[S0];
#pragma unroll
        for (int j = 0; j < S0; ++j) idx[j] = nb[j];
        float4 sv = ((const float4*)(feat + (size_t)self_idx * D))[lane];
        float4 v[S0];
#pragma unroll
        for (int j = 0; j < S0; ++j)
            v[j] = ((const float4*)(feat + (size_t)idx[j] * D))[lane];
        __builtin_amdgcn_sched_barrier(0);
        float4 acc = make_float4(0.f, 0.f, 0.f, 0.f);
#pragma unroll
        for (int j = 0; j < S0; ++j) {
            acc.x += v[j].x; acc.y += v[j].y; acc.z += v[j].z; acc.w += v[j].w;
        }
        const float s25 = 1.0f / 25.0f;
        bf16x4 svb = { (__bf16)sv.x, (__bf16)sv.y, (__bf16)sv.z, (__bf16)sv.w };
        bf16x4 avb = { (__bf16)(acc.x * s25), (__bf16)(acc.y * s25),
                       (__bf16)(acc.z * s25), (__bf16)(acc.w * s25) };
        // self dims [4l,4l+4) -> granule l>>1 (half l&1); agg dims +256 -> +32 granules
        const int sw = r & 7;
        const int gs = (lane >> 1) ^ sw;
        const int ga = (32 + (lane >> 1)) ^ sw;
        *(bf16x4*)(Atile + (size_t)r * 512 + gs * 8 + (lane & 1) * 4) = svb;
        *(bf16x4*)(Atile + (size_t)r * 512 + ga * 8 + (lane & 1) * 4) = avb;
    }
    __syncthreads();

    // ---- GEMM phase: 8 k-tiles of 64, 3 row-fragments ----
    f32x4 acc[3][4];
#pragma unroll
    for (int rf = 0; rf < 3; ++rf)
#pragma unroll
        for (int nf = 0; nf < 4; ++nf) acc[rf][nf] = (f32x4){0.f, 0.f, 0.f, 0.f};

    for (int k0 = 0; k0 < K2; k0 += 64) {
        // write Bs from prefetched bf16 regs (linear in tid)
#pragma unroll
        for (int s = 0; s < 8; ++s)
            *(uint4*)(Bs + (size_t)(tid + s * 256) * 8) = rb[s];
        __syncthreads();
        if (k0 + 64 < K2) {
#pragma unroll
            for (int s = 0; s < 8; ++s) {
                int i = tid + s * 256;
                int cg = i >> 7, kc = (i >> 4) & 7, lo = i & 15;
                rb[s] = *(const uint4*)(Wb0 + (size_t)(cg * 16 + lo) * K2 + (k0 + 64) + kc * 8);
            }
        }
#pragma unroll
        for (int kf = 0; kf < 2; ++kf) {
            const int kc = kf * 4 + g;
            const int gA = (k0 >> 3) + kc;  // granule index within a row
            bf16x8 af[3], bfr[4];
#pragma unroll
            for (int rf = 0; rf < 3; ++rf) {
                int row = rf * 16 + rl;
                af[rf] = *(const bf16x8*)(Atile + (size_t)row * 512 +
                                          (size_t)(gA ^ (row & 7)) * 8);
            }
#pragma unroll
            for (int nf = 0; nf < 4; ++nf)
                bfr[nf] = *(const bf16x8*)(Bs + ((size_t)((w * 4 + nf) * 8 + kc) * 16 + rl) * 8);
#pragma unroll
            for (int rf = 0; rf < 3; ++rf)
#pragma unroll
                for (int nf = 0; nf < 4; ++nf)
                    acc[rf][nf] = __builtin_amdgcn_mfma_f32_16x16x32_bf16(
                        af[rf], bfr[nf], acc[rf][nf], 0, 0, 0);
        }
        __syncthreads();
    }

    // ---- epilogue: bias + relu + row L2 norm + store bf16 (rows < 44) ----
    float bv[4];
#pragma unroll
    for (int nf = 0; nf < 4; ++nf) bv[nf] = b0[w * 64 + nf * 16 + rl];

#pragma unroll
    for (int rf = 0; rf < 3; ++rf) {
        float ss0 = 0.f, ss1 = 0.f, ss2 = 0.f, ss3 = 0.f;
#pragma unroll
        for (int nf = 0; nf < 4; ++nf) {
            float v0 = fmaxf(acc[rf][nf][0] + bv[nf], 0.f);
            float v1 = fmaxf(acc[rf][nf][1] + bv[nf], 0.f);
            float v2 = fmaxf(acc[rf][nf][2] + bv[nf], 0.f);
            float v3 = fmaxf(acc[rf][nf][3] + bv[nf], 0.f);
            acc[rf][nf][0] = v0; acc[rf][nf][1] = v1;
            acc[rf][nf][2] = v2; acc[rf][nf][3] = v3;
            ss0 += v0 * v0; ss1 += v1 * v1; ss2 += v2 * v2; ss3 += v3 * v3;
        }
#pragma unroll
        for (int m = 1; m < 16; m <<= 1) {
            ss0 += __shfl_xor(ss0, m);
            ss1 += __shfl_xor(ss1, m);
            ss2 += __shfl_xor(ss2, m);
            ss3 += __shfl_xor(ss3, m);
        }
        float ssv = (rl == 0) ? ss0 : (rl == 1) ? ss1 : (rl == 2) ? ss2 : ss3;
        if (rl < 4) ssLDS[w][rf * 16 + g * 4 + rl] = ssv;
    }
    __syncthreads();
    if (tid < RP) {
        float t = ssLDS[0][tid] + ssLDS[1][tid] + ssLDS[2][tid] + ssLDS[3][tid];
        invLDS[tid] = (t > 0.f) ? rsqrtf(t) : 1.0f;
    }
    __syncthreads();
#pragma unroll
    for (int rf = 0; rf < 3; ++rf)
#pragma unroll
        for (int j = 0; j < 4; ++j) {
            const int row = rf * 16 + g * 4 + j;
            if (row < RB0) {
                const float inv = invLDS[row];
#pragma unroll
                for (int nf = 0; nf < 4; ++nf)
                    h1b[(size_t)(row0 + row) * D + w * 64 + nf * 16 + rl] =
                        (__bf16)(acc[rf][nf][j] * inv);
            }
        }
}

// ---------------------------------------------------------------------------
// fused_layer1 (R15 champion + bf16 B-staging): Out[1024][256] =
// l2norm(relu(X1 @ W1^T + b1)); X1 row i = [h1[i] | mean_j h1[1024+i*10+j]]
// built on the fly. A (areg[10]) and B reg-prefetched one k-tile ahead.
// W1 staged as bf16 (halves its 512KB/CU load-pipe cost on 64 active CUs).
// launch_bounds(256,1): 64 blocks on 256 CUs, never 2/CU.
// ---------------------------------------------------------------------------
__global__ __launch_bounds__(256, 1) void fused_layer1(
        const __bf16* __restrict__ h1, const __bf16* __restrict__ Wb1,
        const float* __restrict__ b1, float* __restrict__ Out) {
    constexpr int RB = 32;
    __shared__ __bf16 As[RB * 64];
    __shared__ __bf16 Bs[256 * 64];
    __shared__ float ssLDS[4][RB];
    __shared__ float invLDS[RB];

    const int tid = threadIdx.x;
    const int row0 = blockIdx.x * RB;
    const int lane = tid & 63;
    const int w = tid >> 6;
    const int rl = lane & 15;
    const int g = lane >> 4;
    const int rg = tid >> 7, kc8 = (tid >> 4) & 7, lo = tid & 15;
    const int grow = row0 + rg * 16 + lo;

    bf16x8 areg[S1];
    uint4 rb[8];
    int acur = 1;   // 1 = self phase (areg[0] valid), S1 = agg phase

    areg[0] = *(const bf16x8*)(h1 + (size_t)grow * D + kc8 * 8);
#pragma unroll
    for (int s = 0; s < 8; ++s) {
        int i = tid + s * 256;
        int cg = i >> 7, kc = (i >> 4) & 7, blo = i & 15;
        rb[s] = *(const uint4*)(Wb1 + (size_t)(cg * 16 + blo) * K2 + kc * 8);
    }

    f32x4 acc[2][4];
#pragma unroll
    for (int rf = 0; rf < 2; ++rf)
#pragma unroll
        for (int nf = 0; nf < 4; ++nf) acc[rf][nf] = (f32x4){0.f, 0.f, 0.f, 0.f};

    for (int k0 = 0; k0 < K2; k0 += 64) {
        bf16x8 av;
        if (acur == 1) {
            av = areg[0];
        } else {
            float f[8];
#pragma unroll
            for (int e = 0; e < 8; ++e) f[e] = 0.f;
#pragma unroll
            for (int j = 0; j < S1; ++j)
#pragma unroll
                for (int e = 0; e < 8; ++e) f[e] += (float)areg[j][e];
#pragma unroll
            for (int e = 0; e < 8; ++e) av[e] = (__bf16)(f[e] * 0.1f);
        }
        *(bf16x8*)(As + (size_t)tid * 8) = av;
#pragma unroll
        for (int s = 0; s < 8; ++s)
            *(uint4*)(Bs + (size_t)(tid + s * 256) * 8) = rb[s];
        __syncthreads();
        if (k0 + 64 < K2) {
            const int kn = k0 + 64;
            if (kn < 256) {
                areg[0] = *(const bf16x8*)(h1 + (size_t)grow * D + kn + kc8 * 8);
                acur = 1;
            } else {
                const __bf16* base = h1 + (size_t)(BATCH + grow * S1) * D + (kn - 256) + kc8 * 8;
#pragma unroll
                for (int j = 0; j < S1; ++j)
                    areg[j] = *(const bf16x8*)(base + (size_t)j * D);
                acur = S1;
            }
#pragma unroll
            for (int s = 0; s < 8; ++s) {
                int i = tid + s * 256;
                int cg = i >> 7, kc = (i >> 4) & 7, blo = i & 15;
                rb[s] = *(const uint4*)(Wb1 + (size_t)(cg * 16 + blo) * K2 + kn + kc * 8);
            }
        }
#pragma unroll
        for (int kf = 0; kf < 2; ++kf) {
            const int kc = kf * 4 + g;
            bf16x8 af[2], bfr[4];
#pragma unroll
            for (int rf = 0; rf < 2; ++rf)
                af[rf] = *(const bf16x8*)(As + ((size_t)(rf * 8 + kc) * 16 + rl) * 8);
#pragma unroll
            for (int nf = 0; nf < 4; ++nf)
                bfr[nf] = *(const bf16x8*)(Bs + ((size_t)((w * 4 + nf) * 8 + kc) * 16 + rl) * 8);
#pragma unroll
            for (int rf = 0; rf < 2; ++rf)
#pragma unroll
                for (int nf = 0; nf < 4; ++nf)
                    acc[rf][nf] = __builtin_amdgcn_mfma_f32_16x16x32_bf16(
                        af[rf], bfr[nf], acc[rf][nf], 0, 0, 0);
        }
        __syncthreads();
    }

    float bv[4];
#pragma unroll
    for (int nf = 0; nf < 4; ++nf) bv[nf] = b1[w * 64 + nf * 16 + rl];

#pragma unroll
    for (int rf = 0; rf < 2; ++rf) {
        float ss0 = 0.f, ss1 = 0.f, ss2 = 0.f, ss3 = 0.f;
#pragma unroll
        for (int nf = 0; nf < 4; ++nf) {
            float v0 = fmaxf(acc[rf][nf][0] + bv[nf], 0.f);
            float v1 = fmaxf(acc[rf][nf][1] + bv[nf], 0.f);
            float v2 = fmaxf(acc[rf][nf][2] + bv[nf], 0.f);
            float v3 = fmaxf(acc[rf][nf][3] + bv[nf], 0.f);
            acc[rf][nf][0] = v0; acc[rf][nf][1] = v1;
            acc[rf][nf][2] = v2; acc[rf][nf][3] = v3;
            ss0 += v0 * v0; ss1 += v1 * v1; ss2 += v2 * v2; ss3 += v3 * v3;
        }
#pragma unroll
        for (int m = 1; m < 16; m <<= 1) {
            ss0 += __shfl_xor(ss0, m);
            ss1 += __shfl_xor(ss1, m);
            ss2 += __shfl_xor(ss2, m);
            ss3 += __shfl_xor(ss3, m);
        }
        float ssv = (rl == 0) ? ss0 : (rl == 1) ? ss1 : (rl == 2) ? ss2 : ss3;
        if (rl < 4) ssLDS[w][rf * 16 + g * 4 + rl] = ssv;
    }
    __syncthreads();
    if (tid < RB) {
        float t = ssLDS[0][tid] + ssLDS[1][tid] + ssLDS[2][tid] + ssLDS[3][tid];
        invLDS[tid] = (t > 0.f) ? rsqrtf(t) : 1.0f;
    }
    __syncthreads();
#pragma unroll
    for (int rf = 0; rf < 2; ++rf)
#pragma unroll
        for (int j = 0; j < 4; ++j) {
            const int row = rf * 16 + g * 4 + j;
            const float inv = invLDS[row];
#pragma unroll
            for (int nf = 0; nf < 4; ++nf)
                Out[(size_t)(row0 + row) * D + w * 64 + nf * 16 + rl] = acc[rf][nf][j] * inv;
        }
}

// ---------------------------------------------------------------------------
extern "C" void kernel_launch(void* const* d_in, const int* in_sizes, int n_in,
                              void* d_out, int out_size, void* d_ws, size_t ws_size,
                              hipStream_t stream) {
    const float* features = (const float*)d_in[0];
    const float* W0       = (const float*)d_in[1];
    const float* b0       = (const float*)d_in[2];
    const float* W1       = (const float*)d_in[3];
    const float* b1       = (const float*)d_in[4];
    const int*   nodes2   = (const int*)d_in[5];
    const int*   neigh2   = (const int*)d_in[6];
    const int*   neigh1   = (const int*)d_in[7];
    float* out = (float*)d_out;

    // workspace layout
    char* ws = (char*)d_ws;
    __bf16* Wb0 = (__bf16*)ws;                     // 256 KB
    __bf16* Wb1 = (__bf16*)(ws + 262144);          // 256 KB
    __bf16* h1b = (__bf16*)(ws + 524288);          // 11264*256*2 = 5.75 MB

    convert_w<<<256, 256, 0, stream>>>(W0, W1, Wb0, Wb1);
    fused_layer0<<<N1 / RB0, 256, 0, stream>>>(features, Wb0, b0, nodes2,
                                               neigh2, neigh1, h1b);
    fused_layer1<<<BATCH / 32, 256, 0, stream>>>(h1b, Wb1, b1, out);
}

// Round 18
// 88.812 us; speedup vs baseline: 1.2950x; 1.2950x over previous
//
#include <hip/hip_runtime.h>
#include <math.h>

#define D 256
#define K2 512          // 2*D
#define BATCH 1024      // n2
#define N1 11264        // n1 = B*(1+10)
#define S0 25
#define S1 10
#define RB0 44          // rows per layer0 block: 11264/44 = 256 blocks = 1/CU
#define RP 48           // padded rows (3 x 16 fragments)

typedef __bf16 bf16x8 __attribute__((ext_vector_type(8)));
typedef __bf16 bf16x4 __attribute__((ext_vector_type(4)));
typedef float  f32x4  __attribute__((ext_vector_type(4)));

// ---------------------------------------------------------------------------
// fused_layer0 (R16 champion, byte-identical revert):
// RB=44, grid=256 -> EXACTLY 1 block/CU. Per-CU gather rate caps at ~20GB/s
// and is insensitive to waves/MLP/LDS (R8-R13 probes); the wall is the
// most-loaded CU, so a balanced grid is optimal. fp32 W0 staging is kept:
// bf16 staging destabilizes codegen (R14: v[25] scratch spill; R17: +32KB
// LDS inflation + 29x bank conflicts).
//   phase 1 (gather): wave w gathers rows [11w, 11w+11): self + mean of 25
//     neighbor fp32 rows -> bf16 -> swizzled full-K LDS A-tile [48][512].
//   phase 2 (GEMM): 8 k-tiles of 64; B staged from fp32 W0 with inline bf16
//     cvt (reg-prefetched); 3 row-frags x 4 col-frags per wave.
//   epilogue: bias + relu + row-l2norm -> h1b (bf16), rows < 44 only.
// Fragment mapping (m89): A/B lane l: row/col=l&15, k=(l>>4)*8+i.
// C/D: col=l&15, row=(l>>4)*4+reg.
// ---------------------------------------------------------------------------
__global__ __launch_bounds__(256, 2) void fused_layer0(
        const float* __restrict__ feat, const float* __restrict__ W0,
        const float* __restrict__ b0, const int* __restrict__ nodes2,
        const int* __restrict__ neigh2, const int* __restrict__ neigh1,
        __bf16* __restrict__ h1b) {
    __shared__ __bf16 Atile[RP * 512];   // 48KB, swizzled granules of 8 bf16
    __shared__ __bf16 Bs[256 * 64];      // 32KB, tile16 layout
    __shared__ float ssLDS[4][RP];
    __shared__ float invLDS[RP];

    const int tid = threadIdx.x;
    const int lane = tid & 63;
    const int w = tid >> 6;
    const int rl = lane & 15;
    const int g = lane >> 4;
    const int row0 = blockIdx.x * RB0;

    // ---- B prologue loads (k0 = 0), fp32, 2 float4 per slot ----
    float4 rb0[8], rb1[8];
#pragma unroll
    for (int s = 0; s < 8; ++s) {
        int i = tid + s * 256;
        int cg = i >> 7, kc = (i >> 4) & 7, lo = i & 15;
        const float* p = W0 + (size_t)(cg * 16 + lo) * K2 + kc * 8;
        rb0[s] = *(const float4*)p;
        rb1[s] = *(const float4*)(p + 4);
    }

    // ---- gather phase: wave w handles rows [11w, 11w+11) ----
#pragma unroll 1
    for (int r = w * 11; r < w * 11 + 11; ++r) {
        const int gr = row0 + r;
        const int self_idx = (gr < BATCH) ? nodes2[gr] : neigh2[gr - BATCH];
        const int* nb = neigh1 + (size_t)gr * S0;
        int idx[S0];
#pragma unroll
        for (int j = 0; j < S0; ++j) idx[j] = nb[j];
        float4 sv = ((const float4*)(feat + (size_t)self_idx * D))[lane];
        float4 v[S0];
#pragma unroll
        for (int j = 0; j < S0; ++j)
            v[j] = ((const float4*)(feat + (size_t)idx[j] * D))[lane];
        __builtin_amdgcn_sched_barrier(0);
        float4 acc = make_float4(0.f, 0.f, 0.f, 0.f);
#pragma unroll
        for (int j = 0; j < S0; ++j) {
            acc.x += v[j].x; acc.y += v[j].y; acc.z += v[j].z; acc.w += v[j].w;
        }
        const float s25 = 1.0f / 25.0f;
        bf16x4 svb = { (__bf16)sv.x, (__bf16)sv.y, (__bf16)sv.z, (__bf16)sv.w };
        bf16x4 avb = { (__bf16)(acc.x * s25), (__bf16)(acc.y * s25),
                       (__bf16)(acc.z * s25), (__bf16)(acc.w * s25) };
        // self dims [4l,4l+4) -> granule l>>1 (half l&1); agg dims +256 -> +32 granules
        const int sw = r & 7;
        const int gs = (lane >> 1) ^ sw;
        const int ga = (32 + (lane >> 1)) ^ sw;
        *(bf16x4*)(Atile + (size_t)r * 512 + gs * 8 + (lane & 1) * 4) = svb;
        *(bf16x4*)(Atile + (size_t)r * 512 + ga * 8 + (lane & 1) * 4) = avb;
    }
    __syncthreads();

    // ---- GEMM phase: 8 k-tiles of 64, 3 row-fragments ----
    f32x4 acc[3][4];
#pragma unroll
    for (int rf = 0; rf < 3; ++rf)
#pragma unroll
        for (int nf = 0; nf < 4; ++nf) acc[rf][nf] = (f32x4){0.f, 0.f, 0.f, 0.f};

    for (int k0 = 0; k0 < K2; k0 += 64) {
        // write Bs from prefetched fp32 regs with inline cvt (linear in tid)
#pragma unroll
        for (int s = 0; s < 8; ++s) {
            int i = tid + s * 256;
            bf16x8 bv;
            bv[0] = (__bf16)rb0[s].x; bv[1] = (__bf16)rb0[s].y;
            bv[2] = (__bf16)rb0[s].z; bv[3] = (__bf16)rb0[s].w;
            bv[4] = (__bf16)rb1[s].x; bv[5] = (__bf16)rb1[s].y;
            bv[6] = (__bf16)rb1[s].z; bv[7] = (__bf16)rb1[s].w;
            *(bf16x8*)(Bs + (size_t)i * 8) = bv;
        }
        __syncthreads();
        if (k0 + 64 < K2) {
#pragma unroll
            for (int s = 0; s < 8; ++s) {
                int i = tid + s * 256;
                int cg = i >> 7, kc = (i >> 4) & 7, lo = i & 15;
                const float* p = W0 + (size_t)(cg * 16 + lo) * K2 + (k0 + 64) + kc * 8;
                rb0[s] = *(const float4*)p;
                rb1[s] = *(const float4*)(p + 4);
            }
        }
#pragma unroll
        for (int kf = 0; kf < 2; ++kf) {
            const int kc = kf * 4 + g;
            const int gA = (k0 >> 3) + kc;  // granule index within a row
            bf16x8 af[3], bfr[4];
#pragma unroll
            for (int rf = 0; rf < 3; ++rf) {
                int row = rf * 16 + rl;
                af[rf] = *(const bf16x8*)(Atile + (size_t)row * 512 +
                                          (size_t)(gA ^ (row & 7)) * 8);
            }
#pragma unroll
            for (int nf = 0; nf < 4; ++nf)
                bfr[nf] = *(const bf16x8*)(Bs + ((size_t)((w * 4 + nf) * 8 + kc) * 16 + rl) * 8);
#pragma unroll
            for (int rf = 0; rf < 3; ++rf)
#pragma unroll
                for (int nf = 0; nf < 4; ++nf)
                    acc[rf][nf] = __builtin_amdgcn_mfma_f32_16x16x32_bf16(
                        af[rf], bfr[nf], acc[rf][nf], 0, 0, 0);
        }
        __syncthreads();
    }

    // ---- epilogue: bias + relu + row L2 norm + store bf16 (rows < 44) ----
    float bv[4];
#pragma unroll
    for (int nf = 0; nf < 4; ++nf) bv[nf] = b0[w * 64 + nf * 16 + rl];

#pragma unroll
    for (int rf = 0; rf < 3; ++rf) {
        float ss0 = 0.f, ss1 = 0.f, ss2 = 0.f, ss3 = 0.f;
#pragma unroll
        for (int nf = 0; nf < 4; ++nf) {
            float v0 = fmaxf(acc[rf][nf][0] + bv[nf], 0.f);
            float v1 = fmaxf(acc[rf][nf][1] + bv[nf], 0.f);
            float v2 = fmaxf(acc[rf][nf][2] + bv[nf], 0.f);
            float v3 = fmaxf(acc[rf][nf][3] + bv[nf], 0.f);
            acc[rf][nf][0] = v0; acc[rf][nf][1] = v1;
            acc[rf][nf][2] = v2; acc[rf][nf][3] = v3;
            ss0 += v0 * v0; ss1 += v1 * v1; ss2 += v2 * v2; ss3 += v3 * v3;
        }
#pragma unroll
        for (int m = 1; m < 16; m <<= 1) {
            ss0 += __shfl_xor(ss0, m);
            ss1 += __shfl_xor(ss1, m);
            ss2 += __shfl_xor(ss2, m);
            ss3 += __shfl_xor(ss3, m);
        }
        float ssv = (rl == 0) ? ss0 : (rl == 1) ? ss1 : (rl == 2) ? ss2 : ss3;
        if (rl < 4) ssLDS[w][rf * 16 + g * 4 + rl] = ssv;
    }
    __syncthreads();
    if (tid < RP) {
        float t = ssLDS[0][tid] + ssLDS[1][tid] + ssLDS[2][tid] + ssLDS[3][tid];
        invLDS[tid] = (t > 0.f) ? rsqrtf(t) : 1.0f;
    }
    __syncthreads();
#pragma unroll
    for (int rf = 0; rf < 3; ++rf)
#pragma unroll
        for (int j = 0; j < 4; ++j) {
            const int row = rf * 16 + g * 4 + j;
            if (row < RB0) {
                const float inv = invLDS[row];
#pragma unroll
                for (int nf = 0; nf < 4; ++nf)
                    h1b[(size_t)(row0 + row) * D + w * 64 + nf * 16 + rl] =
                        (__bf16)(acc[rf][nf][j] * inv);
            }
        }
}

// ---------------------------------------------------------------------------
// fused_layer1 (R15 champion, byte-identical): Out[1024][256] = l2norm(relu(
// X1 @ W1^T + b1)); X1 row i = [h1[i] | mean_j h1[1024+i*10+j]] built on the
// fly. Both A (areg[10]) and B reg-prefetched one k-tile ahead. RB=32.
// fp32 W1 staging kept (R17: bf16 staging regressed codegen).
// ---------------------------------------------------------------------------
__global__ __launch_bounds__(256, 2) void fused_layer1(
        const __bf16* __restrict__ h1, const float* __restrict__ W1,
        const float* __restrict__ b1, float* __restrict__ Out) {
    constexpr int RB = 32;
    __shared__ __bf16 As[RB * 64];
    __shared__ __bf16 Bs[256 * 64];
    __shared__ float ssLDS[4][RB];
    __shared__ float invLDS[RB];

    const int tid = threadIdx.x;
    const int row0 = blockIdx.x * RB;
    const int lane = tid & 63;
    const int w = tid >> 6;
    const int rl = lane & 15;
    const int g = lane >> 4;
    const int rg = tid >> 7, kc8 = (tid >> 4) & 7, lo = tid & 15;
    const int grow = row0 + rg * 16 + lo;

    bf16x8 areg[S1];
    float4 rb0[8], rb1[8];
    int acur = 1;   // 1 = self phase (areg[0] valid), S1 = agg phase

    areg[0] = *(const bf16x8*)(h1 + (size_t)grow * D + kc8 * 8);
#pragma unroll
    for (int s = 0; s < 8; ++s) {
        int i = tid + s * 256;
        int cg = i >> 7, kc = (i >> 4) & 7, blo = i & 15;
        const float* p = W1 + (size_t)(cg * 16 + blo) * K2 + kc * 8;
        rb0[s] = *(const float4*)p;
        rb1[s] = *(const float4*)(p + 4);
    }

    f32x4 acc[2][4];
#pragma unroll
    for (int rf = 0; rf < 2; ++rf)
#pragma unroll
        for (int nf = 0; nf < 4; ++nf) acc[rf][nf] = (f32x4){0.f, 0.f, 0.f, 0.f};

    for (int k0 = 0; k0 < K2; k0 += 64) {
        bf16x8 av;
        if (acur == 1) {
            av = areg[0];
        } else {
            float f[8];
#pragma unroll
            for (int e = 0; e < 8; ++e) f[e] = 0.f;
#pragma unroll
            for (int j = 0; j < S1; ++j)
#pragma unroll
                for (int e = 0; e < 8; ++e) f[e] += (float)areg[j][e];
#pragma unroll
            for (int e = 0; e < 8; ++e) av[e] = (__bf16)(f[e] * 0.1f);
        }
        *(bf16x8*)(As + (size_t)tid * 8) = av;
#pragma unroll
        for (int s = 0; s < 8; ++s) {
            int i = tid + s * 256;
            bf16x8 bb;
            bb[0] = (__bf16)rb0[s].x; bb[1] = (__bf16)rb0[s].y;
            bb[2] = (__bf16)rb0[s].z; bb[3] = (__bf16)rb0[s].w;
            bb[4] = (__bf16)rb1[s].x; bb[5] = (__bf16)rb1[s].y;
            bb[6] = (__bf16)rb1[s].z; bb[7] = (__bf16)rb1[s].w;
            *(bf16x8*)(Bs + (size_t)i * 8) = bb;
        }
        __syncthreads();
        if (k0 + 64 < K2) {
            const int kn = k0 + 64;
            if (kn < 256) {
                areg[0] = *(const bf16x8*)(h1 + (size_t)grow * D + kn + kc8 * 8);
                acur = 1;
            } else {
                const __bf16* base = h1 + (size_t)(BATCH + grow * S1) * D + (kn - 256) + kc8 * 8;
#pragma unroll
                for (int j = 0; j < S1; ++j)
                    areg[j] = *(const bf16x8*)(base + (size_t)j * D);
                acur = S1;
            }
#pragma unroll
            for (int s = 0; s < 8; ++s) {
                int i = tid + s * 256;
                int cg = i >> 7, kc = (i >> 4) & 7, blo = i & 15;
                const float* p = W1 + (size_t)(cg * 16 + blo) * K2 + kn + kc * 8;
                rb0[s] = *(const float4*)p;
                rb1[s] = *(const float4*)(p + 4);
            }
        }
#pragma unroll
        for (int kf = 0; kf < 2; ++kf) {
            const int kc = kf * 4 + g;
            bf16x8 af[2], bfr[4];
#pragma unroll
            for (int rf = 0; rf < 2; ++rf)
                af[rf] = *(const bf16x8*)(As + ((size_t)(rf * 8 + kc) * 16 + rl) * 8);
#pragma unroll
            for (int nf = 0; nf < 4; ++nf)
                bfr[nf] = *(const bf16x8*)(Bs + ((size_t)((w * 4 + nf) * 8 + kc) * 16 + rl) * 8);
#pragma unroll
            for (int rf = 0; rf < 2; ++rf)
#pragma unroll
                for (int nf = 0; nf < 4; ++nf)
                    acc[rf][nf] = __builtin_amdgcn_mfma_f32_16x16x32_bf16(
                        af[rf], bfr[nf], acc[rf][nf], 0, 0, 0);
        }
        __syncthreads();
    }

    float bv[4];
#pragma unroll
    for (int nf = 0; nf < 4; ++nf) bv[nf] = b1[w * 64 + nf * 16 + rl];

#pragma unroll
    for (int rf = 0; rf < 2; ++rf) {
        float ss0 = 0.f, ss1 = 0.f, ss2 = 0.f, ss3 = 0.f;
#pragma unroll
        for (int nf = 0; nf < 4; ++nf) {
            float v0 = fmaxf(acc[rf][nf][0] + bv[nf], 0.f);
            float v1 = fmaxf(acc[rf][nf][1] + bv[nf], 0.f);
            float v2 = fmaxf(acc[rf][nf][2] + bv[nf], 0.f);
            float v3 = fmaxf(acc[rf][nf][3] + bv[nf], 0.f);
            acc[rf][nf][0] = v0; acc[rf][nf][1] = v1;
            acc[rf][nf][2] = v2; acc[rf][nf][3] = v3;
            ss0 += v0 * v0; ss1 += v1 * v1; ss2 += v2 * v2; ss3 += v3 * v3;
        }
#pragma unroll
        for (int m = 1; m < 16; m <<= 1) {
            ss0 += __shfl_xor(ss0, m);
            ss1 += __shfl_xor(ss1, m);
            ss2 += __shfl_xor(ss2, m);
            ss3 += __shfl_xor(ss3, m);
        }
        float ssv = (rl == 0) ? ss0 : (rl == 1) ? ss1 : (rl == 2) ? ss2 : ss3;
        if (rl < 4) ssLDS[w][rf * 16 + g * 4 + rl] = ssv;
    }
    __syncthreads();
    if (tid < RB) {
        float t = ssLDS[0][tid] + ssLDS[1][tid] + ssLDS[2][tid] + ssLDS[3][tid];
        invLDS[tid] = (t > 0.f) ? rsqrtf(t) : 1.0f;
    }
    __syncthreads();
#pragma unroll
    for (int rf = 0; rf < 2; ++rf)
#pragma unroll
        for (int j = 0; j < 4; ++j) {
            const int row = rf * 16 + g * 4 + j;
            const float inv = invLDS[row];
#pragma unroll
            for (int nf = 0; nf < 4; ++nf)
                Out[(size_t)(row0 + row) * D + w * 64 + nf * 16 + rl] = acc[rf][nf][j] * inv;
        }
}

// ---------------------------------------------------------------------------
extern "C" void kernel_launch(void* const* d_in, const int* in_sizes, int n_in,
                              void* d_out, int out_size, void* d_ws, size_t ws_size,
                              hipStream_t stream) {
    const float* features = (const float*)d_in[0];
    const float* W0       = (const float*)d_in[1];
    const float* b0       = (const float*)d_in[2];
    const float* W1       = (const float*)d_in[3];
    const float* b1       = (const float*)d_in[4];
    const int*   nodes2   = (const int*)d_in[5];
    const int*   neigh2   = (const int*)d_in[6];
    const int*   neigh1   = (const int*)d_in[7];
    float* out = (float*)d_out;

    __bf16* h1b = (__bf16*)d_ws;   // 11264*256*2 = 5.75 MB

    fused_layer0<<<N1 / RB0, 256, 0, stream>>>(features, W0, b0, nodes2, neigh2,
                                               neigh1, h1b);
    fused_layer1<<<BATCH / 32, 256, 0, stream>>>(h1b, W1, b1, out);
}